// Round 1
// baseline (219.422 us; speedup 1.0000x reference)
//
#include <hip/hip_runtime.h>
#include <cmath>

#define Bz 4
#define Tz 1000
#define Wz 32
#define Dz 200
#define EDz 400
#define Nz 16
#define DTRz 13
#define Lz 1001
#define POSz 500
#define LPz 501
#define NEG_BIG -1e30f

__device__ __forceinline__ float wave_sum(float v) {
#pragma unroll
  for (int o = 32; o; o >>= 1) v += __shfl_xor(v, o);
  return v;
}

// Attention-pool words -> tweet vector -> RMSNorm, writing xn[b, l, :] with
// the CLS slot (l==POS) left for k_cls. Skips masked words/tweets entirely.
__global__ __launch_bounds__(256) void k_pool(
    const float* __restrict__ x, const int* __restrict__ n_tweets,
    const int* __restrict__ n_words, const float* __restrict__ w_attn,
    const float* __restrict__ b_attn, const float* __restrict__ norm_w,
    float* __restrict__ xn) {
  int blk = blockIdx.x;
  int b = blk / Tz, t = blk - b * Tz;
  int l = (t < POSz) ? t : t + 1;
  int tid = threadIdx.x;
  float* outp = xn + ((size_t)b * Lz + l) * Dz;
  int ntw = n_tweets[b]; if (ntw > Tz) ntw = Tz;
  if (t >= ntw) { if (tid < Dz) outp[tid] = 0.f; return; }
  int nw = n_words[b * Tz + t]; if (nw > Wz) nw = Wz; if (nw < 1) nw = 1;
  const float* xs = x + ((size_t)(b * Tz + t)) * (Wz * Dz);
  __shared__ float s_attn[Wz];
  __shared__ float s_red[4];
  // phase A: scores[w] = dot(x[w,:], w_attn), 8 lanes per word
  int w = tid >> 3, j = tid & 7;
  float sc = 0.f;
  if (w < nw) {
    for (int d = j * 4; d < Dz; d += 32) {
      float4 xv = *(const float4*)(xs + w * Dz + d);
      float4 wv = *(const float4*)(w_attn + d);
      sc += xv.x * wv.x + xv.y * wv.y + xv.z * wv.z + xv.w * wv.w;
    }
  }
  sc += __shfl_xor(sc, 1); sc += __shfl_xor(sc, 2); sc += __shfl_xor(sc, 4);
  if (j == 0) s_attn[w] = (w < nw) ? (sc + b_attn[0]) : NEG_BIG;
  __syncthreads();
  // phase B: softmax over valid words (wave 0)
  if (tid < 64) {
    float s = (tid < Wz) ? s_attn[tid] : NEG_BIG;
    float m = s;
#pragma unroll
    for (int o = 32; o; o >>= 1) m = fmaxf(m, __shfl_xor(m, o));
    float e = (s > 0.5f * NEG_BIG) ? __expf(s - m) : 0.f;
    float tot = wave_sum(e);
    if (tid < Wz) s_attn[tid] = e / tot;
  }
  __syncthreads();
  // phase C: weighted sum over valid words (L1-resident re-read) + RMSNorm
  float val = 0.f;
  if (tid < Dz) {
    for (int ww = 0; ww < nw; ++ww) val += s_attn[ww] * xs[ww * Dz + tid];
  }
  float sq = wave_sum(val * val);
  if ((tid & 63) == 0) s_red[tid >> 6] = sq;
  __syncthreads();
  float tot = s_red[0] + s_red[1] + s_red[2] + s_red[3];
  float scale = rsqrtf(tot * (1.f / Dz) + 1e-5f);
  if (tid < Dz) outp[tid] = val * scale * norm_w[tid];
}

__global__ __launch_bounds__(256) void k_cls(
    const float* __restrict__ cls, const float* __restrict__ norm_w,
    float* __restrict__ xn) {
  int tid = threadIdx.x;
  __shared__ float s_red[4];
  float val = (tid < Dz) ? cls[tid] : 0.f;
  float sq = wave_sum(val * val);
  if ((tid & 63) == 0) s_red[tid >> 6] = sq;
  __syncthreads();
  float tot = s_red[0] + s_red[1] + s_red[2] + s_red[3];
  float scale = rsqrtf(tot * (1.f / Dz) + 1e-5f);
  if (tid < Dz) {
    float o = val * scale * norm_w[tid];
#pragma unroll
    for (int b = 0; b < Bz; ++b) xn[((size_t)b * Lz + POSz) * Dz + tid] = o;
  }
}

// xp_pre[b, t, e] = xn[b, local(t), :] @ in_proj[:, e], t in [0,501)
// local(t) = t (fwd) or L-1-t (bwd). 8 rows per block to amortize in_proj.
__global__ __launch_bounds__(512) void k_inproj(
    const float* __restrict__ xn, const float* __restrict__ in_proj, int rev,
    float* __restrict__ xp_pre) {
  int blk = blockIdx.x;
  int b = blk / 63, t0 = (blk - b * 63) * 8;
  int tid = threadIdx.x;
  __shared__ float xs[8 * Dz];
  for (int idx = tid; idx < 8 * Dz; idx += 512) {
    int r = idx / Dz, d = idx - r * Dz;
    int t = t0 + r;
    float v = 0.f;
    if (t < LPz) {
      int tl = rev ? (Lz - 1 - t) : t;
      v = xn[((size_t)b * Lz + tl) * Dz + d];
    }
    xs[idx] = v;
  }
  __syncthreads();
  if (tid < EDz) {
    float acc[8] = {0.f, 0.f, 0.f, 0.f, 0.f, 0.f, 0.f, 0.f};
    for (int d = 0; d < Dz; ++d) {
      float wv = in_proj[d * (2 * EDz) + tid];
#pragma unroll
      for (int r = 0; r < 8; ++r) acc[r] += xs[r * Dz + d] * wv;
    }
#pragma unroll
    for (int r = 0; r < 8; ++r) {
      int t = t0 + r;
      if (t < LPz) xp_pre[((size_t)b * LPz + t) * EDz + tid] = acc[r];
    }
  }
}

// conv+silu -> xp ; xp @ xproj -> (delta, Bm, Cm) ; dt = softplus(delta@dtw+dtb)
__global__ __launch_bounds__(512) void k_convproj(
    const float* __restrict__ xp_pre, const float* __restrict__ conv_w,
    const float* __restrict__ conv_b, const float* __restrict__ xproj,
    const float* __restrict__ dtw, const float* __restrict__ dtb,
    float* __restrict__ xp, float* __restrict__ dt, float* __restrict__ Bm,
    float* __restrict__ Cend) {
  int blk = blockIdx.x;
  int b = blk / LPz, t = blk - b * LPz;
  int tid = threadIdx.x;
  __shared__ float sx[EDz];
  __shared__ float sdbc[45];
  if (tid < EDz) {
    float4 cw = *(const float4*)(conv_w + tid * 4);
    float wk[4] = {cw.x, cw.y, cw.z, cw.w};
    float acc = conv_b[tid];
#pragma unroll
    for (int k = 0; k < 4; ++k) {
      int ts = t - 3 + k;
      if (ts >= 0) acc += xp_pre[((size_t)b * LPz + ts) * EDz + tid] * wk[k];
    }
    float sp = acc / (1.f + __expf(-acc));  // silu
    sx[tid] = sp;
    xp[((size_t)b * LPz + t) * EDz + tid] = sp;
  }
  __syncthreads();
  if (tid < 360) {  // 45 outputs x 8 lanes
    int jj = tid >> 3, p = tid & 7;
    float acc = 0.f;
    for (int e = p; e < EDz; e += 8) acc += sx[e] * xproj[e * 45 + jj];
    acc += __shfl_xor(acc, 1); acc += __shfl_xor(acc, 2); acc += __shfl_xor(acc, 4);
    if (p == 0) sdbc[jj] = acc;
  }
  __syncthreads();
  if (tid < EDz) {
    float s = dtb[tid];
#pragma unroll
    for (int jj = 0; jj < DTRz; ++jj) s += sdbc[jj] * dtw[jj * EDz + tid];
    float dtv = (s > 20.f) ? s : log1pf(__expf(s));
    dt[((size_t)b * LPz + t) * EDz + tid] = dtv;
  }
  if (tid < Nz) {
    Bm[((size_t)b * LPz + t) * Nz + tid] = sdbc[13 + tid];
    if (t == LPz - 1) Cend[b * Nz + tid] = sdbc[29 + tid];
  }
}

// z at the pos row (both branches read xn[:,500,:])
__global__ __launch_bounds__(512) void k_z(
    const float* __restrict__ xn, const float* __restrict__ ipf,
    const float* __restrict__ ipb, float* __restrict__ z) {
  int b = blockIdx.x >> 1, br = blockIdx.x & 1;
  const float* ip = br ? ipb : ipf;
  int tid = threadIdx.x;
  __shared__ float xs[Dz];
  if (tid < Dz) xs[tid] = xn[((size_t)b * Lz + POSz) * Dz + tid];
  __syncthreads();
  if (tid < EDz) {
    float acc = 0.f;
    for (int d = 0; d < Dz; ++d) acc += xs[d] * ip[d * (2 * EDz) + EDz + tid];
    z[((size_t)br * Bz + b) * EDz + tid] = acc;
  }
}

// v[e] = out_proj[e,:] @ head_w ; also zero the logit accumulator
__global__ __launch_bounds__(512) void k_v(
    const float* __restrict__ out_proj, const float* __restrict__ head_w,
    float* __restrict__ v, float* __restrict__ logit) {
  int tid = threadIdx.x;
  if (tid < Bz) logit[tid] = 0.f;
  __shared__ float hw[Dz];
  if (tid < Dz) hw[tid] = head_w[tid];
  __syncthreads();
  int e0 = tid >> 3, p = tid & 7;
  for (int eb = 0; eb < EDz; eb += 64) {
    int e = eb + e0;
    if (e < EDz) {
      float acc = 0.f;
      for (int d = p * 4; d < Dz; d += 32) {
        float4 ov = *(const float4*)(out_proj + e * Dz + d);
        acc += ov.x * hw[d] + ov.y * hw[d + 1] + ov.z * hw[d + 2] + ov.w * hw[d + 3];
      }
      acc += __shfl_xor(acc, 1); acc += __shfl_xor(acc, 2); acc += __shfl_xor(acc, 4);
      if (p == 0) v[e] = acc;
    }
  }
}

// Parallel "scan": h[pos,e,n] = sum_t exp(A_n*(Stot - S_t)) * dt_t * Bm[t,n] * xp_t
// One wave per (b,e). Then y = C.h + D*xp[pos], contribution y*silu(z)*v[e].
__global__ __launch_bounds__(64) void k_scan(
    const float* __restrict__ xp, const float* __restrict__ dt,
    const float* __restrict__ Bm, const float* __restrict__ Cend,
    const float* __restrict__ A_log, const float* __restrict__ Dp,
    const float* __restrict__ z, const float* __restrict__ v,
    float* __restrict__ logit) {
  int blk = blockIdx.x;
  int b = blk / EDz, e = blk - b * EDz;
  int lane = threadIdx.x;
  float A[Nz];
  {
    const float4* ap = (const float4*)(A_log + e * Nz);
#pragma unroll
    for (int q = 0; q < 4; ++q) {
      float4 a4 = ap[q];
      A[q * 4 + 0] = -__expf(a4.x); A[q * 4 + 1] = -__expf(a4.y);
      A[q * 4 + 2] = -__expf(a4.z); A[q * 4 + 3] = -__expf(a4.w);
    }
  }
  const float* dtp = dt + (size_t)b * LPz * EDz + e;
  const float* xpp = xp + (size_t)b * LPz * EDz + e;
  // pass 1: Stot
  float loc = 0.f;
#pragma unroll
  for (int c = 0; c < 8; ++c) {
    int t = c * 64 + lane;
    if (t < LPz) loc += dtp[(size_t)t * EDz];
  }
  float Stot = wave_sum(loc);
  // pass 2: cumsum + exp-weighted reduction
  float acc[Nz];
#pragma unroll
  for (int n = 0; n < Nz; ++n) acc[n] = 0.f;
  float carry = 0.f;
  for (int c = 0; c < 8; ++c) {
    int t = c * 64 + lane;
    bool act = t < LPz;
    float dtt = act ? dtp[(size_t)t * EDz] : 0.f;
    float s = dtt;
#pragma unroll
    for (int o = 1; o < 64; o <<= 1) {
      float u = __shfl_up(s, o);
      s += (lane >= o) ? u : 0.f;
    }
    float S = carry + s;
    carry += __shfl(s, 63);
    float wt = act ? dtt * xpp[(size_t)t * EDz] : 0.f;
    float decay = Stot - S;  // >= 0
    float bm[Nz];
    if (act) {
      const float4* bp = (const float4*)(Bm + ((size_t)b * LPz + t) * Nz);
#pragma unroll
      for (int q = 0; q < 4; ++q) {
        float4 b4 = bp[q];
        bm[q * 4 + 0] = b4.x; bm[q * 4 + 1] = b4.y;
        bm[q * 4 + 2] = b4.z; bm[q * 4 + 3] = b4.w;
      }
    } else {
#pragma unroll
      for (int n = 0; n < Nz; ++n) bm[n] = 0.f;
    }
#pragma unroll
    for (int n = 0; n < Nz; ++n)
      acc[n] += __expf(A[n] * decay) * wt * bm[n];
  }
#pragma unroll
  for (int o = 32; o; o >>= 1) {
#pragma unroll
    for (int n = 0; n < Nz; ++n) acc[n] += __shfl_xor(acc[n], o);
  }
  if (lane == 0) {
    float y = Dp[e] * xpp[(size_t)(LPz - 1) * EDz];
#pragma unroll
    for (int n = 0; n < Nz; ++n) y += Cend[b * Nz + n] * acc[n];
    float zz = z[b * EDz + e];
    float sz = zz / (1.f + __expf(-zz));
    atomicAdd(&logit[b], y * sz * v[e]);
  }
}

__global__ __launch_bounds__(64) void k_final(
    const float* __restrict__ cls, const float* __restrict__ head_w,
    const float* __restrict__ head_b, const float* __restrict__ logit,
    float* __restrict__ out) {
  int lane = threadIdx.x;
  float acc = 0.f;
  for (int d = lane; d < Dz; d += 64) acc += cls[d] * head_w[d];
  acc = wave_sum(acc);
  if (lane < Bz)
    out[lane] = 1.f / (1.f + __expf(-(logit[lane] + acc + head_b[0])));
}

extern "C" void kernel_launch(void* const* d_in, const int* in_sizes, int n_in,
                              void* d_out, int out_size, void* d_ws, size_t ws_size,
                              hipStream_t stream) {
  const float* input_ids = (const float*)d_in[0];
  const int* n_tweets = (const int*)d_in[1];
  const int* n_words = (const int*)d_in[2];
  const float* cls = (const float*)d_in[3];
  const float* w_attn = (const float*)d_in[4];
  const float* b_attn = (const float*)d_in[5];
  const float* norm_w = (const float*)d_in[6];
  const float* ip[2] = {(const float*)d_in[7], (const float*)d_in[15]};
  const float* cw[2] = {(const float*)d_in[8], (const float*)d_in[16]};
  const float* cb[2] = {(const float*)d_in[9], (const float*)d_in[17]};
  const float* xpj[2] = {(const float*)d_in[10], (const float*)d_in[18]};
  const float* dtw[2] = {(const float*)d_in[11], (const float*)d_in[19]};
  const float* dtbp[2] = {(const float*)d_in[12], (const float*)d_in[20]};
  const float* Alog[2] = {(const float*)d_in[13], (const float*)d_in[21]};
  const float* Dpp[2] = {(const float*)d_in[14], (const float*)d_in[22]};
  const float* out_proj = (const float*)d_in[23];
  const float* head_w = (const float*)d_in[24];
  const float* head_b = (const float*)d_in[25];
  float* out = (float*)d_out;

  float* ws = (float*)d_ws;
  float* xn = ws;                  // 800800
  float* xp_pre = xn + 800800;     // 801600 (shared between branches)
  float* xp_f = xp_pre + 801600;   // 801600
  float* dt_f = xp_f + 801600;     // 801600
  float* Bm_f = dt_f + 801600;     // 32064
  float* xp_b = Bm_f + 32064;      // 801600
  float* dt_b = xp_b + 801600;     // 801600
  float* Bm_b = dt_b + 801600;     // 32064
  float* Cend = Bm_b + 32064;      // 128
  float* zbuf = Cend + 128;        // 3200
  float* vbuf = zbuf + 3200;       // 400
  float* logit = vbuf + 400;       // 4
  // total ~4.88M floats ~19.5 MB

  hipLaunchKernelGGL(k_v, dim3(1), dim3(512), 0, stream, out_proj, head_w, vbuf, logit);
  hipLaunchKernelGGL(k_pool, dim3(Bz * Tz), dim3(256), 0, stream,
                     input_ids, n_tweets, n_words, w_attn, b_attn, norm_w, xn);
  hipLaunchKernelGGL(k_cls, dim3(1), dim3(256), 0, stream, cls, norm_w, xn);
  hipLaunchKernelGGL(k_z, dim3(2 * Bz), dim3(512), 0, stream, xn, ip[0], ip[1], zbuf);

  for (int br = 0; br < 2; ++br) {
    float* xpb = br ? xp_b : xp_f;
    float* dtb_ = br ? dt_b : dt_f;
    float* Bmb = br ? Bm_b : Bm_f;
    float* ce = Cend + br * (Bz * Nz);
    hipLaunchKernelGGL(k_inproj, dim3(Bz * 63), dim3(512), 0, stream,
                       xn, ip[br], br, xp_pre);
    hipLaunchKernelGGL(k_convproj, dim3(Bz * LPz), dim3(512), 0, stream,
                       xp_pre, cw[br], cb[br], xpj[br], dtw[br], dtbp[br],
                       xpb, dtb_, Bmb, ce);
    hipLaunchKernelGGL(k_scan, dim3(Bz * EDz), dim3(64), 0, stream,
                       xpb, dtb_, Bmb, ce, Alog[br], Dpp[br],
                       zbuf + (size_t)br * Bz * EDz, vbuf, logit);
  }
  hipLaunchKernelGGL(k_final, dim3(1), dim3(64), 0, stream,
                     cls, head_w, head_b, logit, out);
}

// Round 2
// 125.431 us; speedup vs baseline: 1.7493x; 1.7493x over previous
//
#include <hip/hip_runtime.h>
#include <cmath>

#define Bz 4
#define Tz 1000
#define Wz 32
#define Dz 200
#define EDz 400
#define Nz 16
#define DTRz 13
#define Lz 1001
#define POSz 500
#define LPz 501
#define NEG_BIG -1e30f

__device__ __forceinline__ float wave_sum(float v) {
#pragma unroll
  for (int o = 32; o; o >>= 1) v += __shfl_xor(v, o);
  return v;
}

// block 0: v[e] = out_proj[e,:]@head_w.  blocks 1..8: (br,b): normalized CLS
// row -> xn[b][POS] (br==0 writers), and z[br][b][e] = cls_n @ in_proj[:,ED+e].
__global__ __launch_bounds__(256) void k_setup(
    const float* __restrict__ cls, const float* __restrict__ norm_w,
    const float* __restrict__ out_proj, const float* __restrict__ head_w,
    const float* __restrict__ ipf, const float* __restrict__ ipb,
    float* __restrict__ xn, float* __restrict__ zbuf, float* __restrict__ vbuf) {
  int bid = blockIdx.x, tid = threadIdx.x;
  if (bid == 0) {
    __shared__ float hw[Dz];
    if (tid < Dz) hw[tid] = head_w[tid];
    __syncthreads();
    for (int e = tid; e < EDz; e += 256) {
      float acc = 0.f;
      for (int d = 0; d < Dz; d += 4) {
        float4 ov = *(const float4*)(out_proj + e * Dz + d);
        acc += ov.x * hw[d] + ov.y * hw[d + 1] + ov.z * hw[d + 2] + ov.w * hw[d + 3];
      }
      vbuf[e] = acc;
    }
    return;
  }
  int id = bid - 1;
  int br = id >> 2, b = id & 3;
  __shared__ float xs[Dz];
  __shared__ float s_red[4];
  float val = (tid < Dz) ? cls[tid] : 0.f;
  float sq = wave_sum(val * val);
  if ((tid & 63) == 0) s_red[tid >> 6] = sq;
  __syncthreads();
  float tot = s_red[0] + s_red[1] + s_red[2] + s_red[3];
  float scale = rsqrtf(tot * (1.f / Dz) + 1e-5f);
  if (tid < Dz) {
    float o = val * scale * norm_w[tid];
    xs[tid] = o;
    if (br == 0) xn[((size_t)b * Lz + POSz) * Dz + tid] = o;
  }
  __syncthreads();
  const float* ip = br ? ipb : ipf;
  for (int e = tid; e < EDz; e += 256) {
    float acc = 0.f;
    for (int d = 0; d < Dz; ++d) acc += xs[d] * ip[d * (2 * EDz) + EDz + e];
    zbuf[((size_t)br * Bz + b) * EDz + e] = acc;
  }
}

// Attention-pool words -> tweet vector -> RMSNorm (unchanged from R0; passed).
__global__ __launch_bounds__(256) void k_pool(
    const float* __restrict__ x, const int* __restrict__ n_tweets,
    const int* __restrict__ n_words, const float* __restrict__ w_attn,
    const float* __restrict__ b_attn, const float* __restrict__ norm_w,
    float* __restrict__ xn) {
  int blk = blockIdx.x;
  int b = blk / Tz, t = blk - b * Tz;
  int l = (t < POSz) ? t : t + 1;
  int tid = threadIdx.x;
  float* outp = xn + ((size_t)b * Lz + l) * Dz;
  int ntw = n_tweets[b]; if (ntw > Tz) ntw = Tz;
  if (t >= ntw) { if (tid < Dz) outp[tid] = 0.f; return; }
  int nw = n_words[b * Tz + t]; if (nw > Wz) nw = Wz; if (nw < 1) nw = 1;
  const float* xs = x + ((size_t)(b * Tz + t)) * (Wz * Dz);
  __shared__ float s_attn[Wz];
  __shared__ float s_red[4];
  int w = tid >> 3, j = tid & 7;
  float sc = 0.f;
  if (w < nw) {
    for (int d = j * 4; d < Dz; d += 32) {
      float4 xv = *(const float4*)(xs + w * Dz + d);
      float4 wv = *(const float4*)(w_attn + d);
      sc += xv.x * wv.x + xv.y * wv.y + xv.z * wv.z + xv.w * wv.w;
    }
  }
  sc += __shfl_xor(sc, 1); sc += __shfl_xor(sc, 2); sc += __shfl_xor(sc, 4);
  if (j == 0) s_attn[w] = (w < nw) ? (sc + b_attn[0]) : NEG_BIG;
  __syncthreads();
  if (tid < 64) {
    float s = (tid < Wz) ? s_attn[tid] : NEG_BIG;
    float m = s;
#pragma unroll
    for (int o = 32; o; o >>= 1) m = fmaxf(m, __shfl_xor(m, o));
    float e = (s > 0.5f * NEG_BIG) ? __expf(s - m) : 0.f;
    float tot = wave_sum(e);
    if (tid < Wz) s_attn[tid] = e / tot;
  }
  __syncthreads();
  float val = 0.f;
  if (tid < Dz) {
    for (int ww = 0; ww < nw; ++ww) val += s_attn[ww] * xs[ww * Dz + tid];
  }
  float sq = wave_sum(val * val);
  if ((tid & 63) == 0) s_red[tid >> 6] = sq;
  __syncthreads();
  float tot = s_red[0] + s_red[1] + s_red[2] + s_red[3];
  float scale = rsqrtf(tot * (1.f / Dz) + 1e-5f);
  if (tid < Dz) outp[tid] = val * scale * norm_w[tid];
}

// Fused: in_proj (with 3-row halo) -> causal conv + silu -> xproj -> dt.
// Writes TRANSPOSED xp_t/dt_t [br][b][e][t] and Bm_t [br][b][n][t] so k_scan
// reads are lane-contiguous. One block per (br, b, 8-row tile).
__global__ __launch_bounds__(512) void k_fused(
    const float* __restrict__ xn,
    const float* __restrict__ ipf, const float* __restrict__ ipb,
    const float* __restrict__ cwf, const float* __restrict__ cwb,
    const float* __restrict__ cbf, const float* __restrict__ cbb,
    const float* __restrict__ xpjf, const float* __restrict__ xpjb,
    const float* __restrict__ dtwf, const float* __restrict__ dtwb,
    const float* __restrict__ dtbf, const float* __restrict__ dtbb,
    float* __restrict__ xp_t, float* __restrict__ dt_t,
    float* __restrict__ Bm_t, float* __restrict__ Cend) {
  int blk = blockIdx.x;
  int br = blk / (Bz * 63);
  int rem = blk - br * (Bz * 63);
  int b = rem / 63, tile = rem - b * 63;
  int t0 = tile * 8;
  int tid = threadIdx.x;
  const float* ip = br ? ipb : ipf;
  const float* cw = br ? cwb : cwf;
  const float* cb = br ? cbb : cbf;
  const float* xpj = br ? xpjb : xpjf;
  const float* dtw = br ? dtwb : dtwf;
  const float* dtb = br ? dtbb : dtbf;

  __shared__ float xs[11 * Dz];
  __shared__ float sx[8 * EDz];
  __shared__ float sdbc[8][45];
  for (int idx = tid; idx < 11 * Dz; idx += 512) {
    int r = idx / Dz, d = idx - r * Dz;
    int lt = t0 - 3 + r;
    float v = 0.f;
    if (lt >= 0 && lt < LPz) {
      int l = br ? (Lz - 1 - lt) : lt;
      v = xn[((size_t)b * Lz + l) * Dz + d];
    }
    xs[idx] = v;
  }
  __syncthreads();
  size_t cbase = (size_t)(br * Bz + b) * EDz * LPz;
  if (tid < EDz) {
    int e = tid;
    float acc[11];
#pragma unroll
    for (int r = 0; r < 11; ++r) acc[r] = 0.f;
    for (int d = 0; d < Dz; ++d) {
      float wv = ip[d * (2 * EDz) + e];
#pragma unroll
      for (int r = 0; r < 11; ++r) acc[r] += xs[r * Dz + d] * wv;
    }
    float4 c4 = *(const float4*)(cw + e * 4);
    float cbv = cb[e];
    float* xpp = xp_t + cbase + (size_t)e * LPz;
#pragma unroll
    for (int r = 0; r < 8; ++r) {
      int t = t0 + r;
      if (t < LPz) {
        float a = cbv + c4.x * acc[r] + c4.y * acc[r + 1] + c4.z * acc[r + 2] + c4.w * acc[r + 3];
        float sp = a / (1.f + __expf(-a));
        sx[r * EDz + e] = sp;
        xpp[t] = sp;
      }
    }
  }
  __syncthreads();
  if (tid < 360) {
    int r = tid / 45, jj = tid - r * 45;
    if (t0 + r < LPz) {
      float acc = 0.f;
      for (int e = 0; e < EDz; ++e) acc += sx[r * EDz + e] * xpj[e * 45 + jj];
      sdbc[r][jj] = acc;
    }
  }
  __syncthreads();
  if (tid < EDz) {
    int e = tid;
    float w13[DTRz];
#pragma unroll
    for (int jj = 0; jj < DTRz; ++jj) w13[jj] = dtw[jj * EDz + e];
    float dtbv = dtb[e];
    float* dtp = dt_t + cbase + (size_t)e * LPz;
#pragma unroll
    for (int r = 0; r < 8; ++r) {
      int t = t0 + r;
      if (t < LPz) {
        float s = dtbv;
#pragma unroll
        for (int jj = 0; jj < DTRz; ++jj) s += sdbc[r][jj] * w13[jj];
        dtp[t] = (s > 20.f) ? s : log1pf(__expf(s));
      }
    }
  } else if (tid < EDz + 128) {
    int q = tid - EDz;
    int r = q >> 4, n = q & 15;
    int t = t0 + r;
    if (t < LPz) {
      Bm_t[((size_t)(br * Bz + b) * Nz + n) * LPz + t] = sdbc[r][13 + n];
      if (t == LPz - 1) Cend[(br * Bz + b) * Nz + n] = sdbc[r][29 + n];
    }
  }
}

// h[end,e,n] = sum_t exp(A_n*(Stot-S_t))*dt_t*Bm[t,n]*xp_t ; all loads
// lane-contiguous via transposed layouts. Writes per-(br,b,e) partial, no atomics.
__global__ __launch_bounds__(64) void k_scan(
    const float* __restrict__ xp_t, const float* __restrict__ dt_t,
    const float* __restrict__ Bm_t, const float* __restrict__ Cend,
    const float* __restrict__ Alogf, const float* __restrict__ Alogb,
    const float* __restrict__ Dpf, const float* __restrict__ Dpb,
    const float* __restrict__ zbuf, const float* __restrict__ vbuf,
    float* __restrict__ ybuf) {
  int blk = blockIdx.x;
  int br = blk / (Bz * EDz);
  int rem = blk - br * (Bz * EDz);
  int b = rem / EDz, e = rem - b * EDz;
  int lane = threadIdx.x;
  const float* A_log = br ? Alogb : Alogf;
  const float* Dp = br ? Dpb : Dpf;
  float A[Nz];
  {
    const float4* ap = (const float4*)(A_log + e * Nz);
#pragma unroll
    for (int q = 0; q < 4; ++q) {
      float4 a4 = ap[q];
      A[q * 4 + 0] = -__expf(a4.x); A[q * 4 + 1] = -__expf(a4.y);
      A[q * 4 + 2] = -__expf(a4.z); A[q * 4 + 3] = -__expf(a4.w);
    }
  }
  size_t base = ((size_t)(br * Bz + b) * EDz + e) * LPz;
  const float* dtp = dt_t + base;
  const float* xpp = xp_t + base;
  const float* bmp = Bm_t + (size_t)(br * Bz + b) * Nz * LPz;
  float loc = 0.f;
#pragma unroll
  for (int c = 0; c < 8; ++c) {
    int t = c * 64 + lane;
    if (t < LPz) loc += dtp[t];
  }
  float Stot = wave_sum(loc);
  float acc[Nz];
#pragma unroll
  for (int n = 0; n < Nz; ++n) acc[n] = 0.f;
  float carry = 0.f;
  for (int c = 0; c < 8; ++c) {
    int t = c * 64 + lane;
    bool act = t < LPz;
    float dtt = 0.f, xv = 0.f;
    if (act) { dtt = dtp[t]; xv = xpp[t]; }
    float s = dtt;
#pragma unroll
    for (int o = 1; o < 64; o <<= 1) {
      float u = __shfl_up(s, o);
      s += (lane >= o) ? u : 0.f;
    }
    float S = carry + s;
    carry += __shfl(s, 63);
    float wt = dtt * xv;
    float decay = Stot - S;  // >= 0, A<0 => exp<=1
#pragma unroll
    for (int n = 0; n < Nz; ++n) {
      float bv = 0.f;
      if (act) bv = bmp[n * LPz + t];
      acc[n] += __expf(A[n] * decay) * wt * bv;
    }
  }
#pragma unroll
  for (int o = 32; o; o >>= 1) {
#pragma unroll
    for (int n = 0; n < Nz; ++n) acc[n] += __shfl_xor(acc[n], o);
  }
  if (lane == 0) {
    float y = Dp[e] * xpp[LPz - 1];
#pragma unroll
    for (int n = 0; n < Nz; ++n) y += Cend[(br * Bz + b) * Nz + n] * acc[n];
    float zz = zbuf[((size_t)br * Bz + b) * EDz + e];
    float sz = zz / (1.f + __expf(-zz));
    ybuf[((size_t)br * Bz + b) * EDz + e] = y * sz * vbuf[e];
  }
}

__global__ __launch_bounds__(256) void k_final(
    const float* __restrict__ cls, const float* __restrict__ head_w,
    const float* __restrict__ head_b, const float* __restrict__ ybuf,
    float* __restrict__ out) {
  int tid = threadIdx.x;
  int b = tid >> 6, lane = tid & 63;
  float acc = 0.f;
  for (int e = lane; e < EDz; e += 64)
    acc += ybuf[(size_t)b * EDz + e] + ybuf[(size_t)(Bz + b) * EDz + e];
  for (int d = lane; d < Dz; d += 64) acc += cls[d] * head_w[d];
  acc = wave_sum(acc);
  if (lane == 0) out[b] = 1.f / (1.f + __expf(-(acc + head_b[0])));
}

extern "C" void kernel_launch(void* const* d_in, const int* in_sizes, int n_in,
                              void* d_out, int out_size, void* d_ws, size_t ws_size,
                              hipStream_t stream) {
  const float* input_ids = (const float*)d_in[0];
  const int* n_tweets = (const int*)d_in[1];
  const int* n_words = (const int*)d_in[2];
  const float* cls = (const float*)d_in[3];
  const float* w_attn = (const float*)d_in[4];
  const float* b_attn = (const float*)d_in[5];
  const float* norm_w = (const float*)d_in[6];
  const float* ip[2] = {(const float*)d_in[7], (const float*)d_in[15]};
  const float* cw[2] = {(const float*)d_in[8], (const float*)d_in[16]};
  const float* cb[2] = {(const float*)d_in[9], (const float*)d_in[17]};
  const float* xpj[2] = {(const float*)d_in[10], (const float*)d_in[18]};
  const float* dtw[2] = {(const float*)d_in[11], (const float*)d_in[19]};
  const float* dtbp[2] = {(const float*)d_in[12], (const float*)d_in[20]};
  const float* Alog[2] = {(const float*)d_in[13], (const float*)d_in[21]};
  const float* Dpp[2] = {(const float*)d_in[14], (const float*)d_in[22]};
  const float* out_proj = (const float*)d_in[23];
  const float* head_w = (const float*)d_in[24];
  const float* head_b = (const float*)d_in[25];
  float* out = (float*)d_out;

  float* ws = (float*)d_ws;
  float* xn = ws;                          // 800800
  float* xp_t = xn + 800800;               // 2*4*400*501 = 1603200
  float* dt_t = xp_t + 1603200;            // 1603200
  float* Bm_t = dt_t + 1603200;            // 2*4*16*501 = 64128 (+pad)
  float* Cend = Bm_t + 64128 + 64;         // 128
  float* zbuf = Cend + 128;                // 3200
  float* vbuf = zbuf + 3200;               // 400
  float* ybuf = vbuf + 400;                // 3200
  // total ~4.08M floats ~16.3 MB

  hipLaunchKernelGGL(k_setup, dim3(9), dim3(256), 0, stream,
                     cls, norm_w, out_proj, head_w, ip[0], ip[1], xn, zbuf, vbuf);
  hipLaunchKernelGGL(k_pool, dim3(Bz * Tz), dim3(256), 0, stream,
                     input_ids, n_tweets, n_words, w_attn, b_attn, norm_w, xn);
  hipLaunchKernelGGL(k_fused, dim3(2 * Bz * 63), dim3(512), 0, stream,
                     xn, ip[0], ip[1], cw[0], cw[1], cb[0], cb[1],
                     xpj[0], xpj[1], dtw[0], dtw[1], dtbp[0], dtbp[1],
                     xp_t, dt_t, Bm_t, Cend);
  hipLaunchKernelGGL(k_scan, dim3(2 * Bz * EDz), dim3(64), 0, stream,
                     xp_t, dt_t, Bm_t, Cend, Alog[0], Alog[1], Dpp[0], Dpp[1],
                     zbuf, vbuf, ybuf);
  hipLaunchKernelGGL(k_final, dim3(1), dim3(256), 0, stream,
                     cls, head_w, head_b, ybuf, out);
}